// Round 3
// baseline (470.679 us; speedup 1.0000x reference)
//
#include <hip/hip_runtime.h>

#define NUM_CLASSES 601
#define OUT_DIM 27
#define P_ELEMS (NUM_CLASSES * OUT_DIM)   // 16227 floats = 64908 B LDS (< 64 KiB static limit)

typedef float vfloat4 __attribute__((ext_vector_type(4)));

// block=1024 (16 waves); LDS 64908 B -> 2 blocks/CU -> 32 waves/CU (max).
// __launch_bounds__(1024, 8) pins VGPR <= 64 so both blocks stay resident.
// Body is deliberately UN-unrolled: ~20 live VGPRs, zero spill risk under the
// 64-VGPR cap. Latency hiding comes from 8 waves/SIMD of TLP, not in-thread MLP.
// Stores are plain float4 (the harness fill kernel proves plain streaming
// stores reach 6.3 TB/s on this buffer; nontemporal removed as a variable).
__global__ __launch_bounds__(1024, 8)
void trigram_probs_kernel(const int* __restrict__ idx,
                          const float* __restrict__ W,
                          float4* __restrict__ out4,
                          unsigned n4) {
    __shared__ float P[P_ELEMS];
    const unsigned t = threadIdx.x;

    // ---- Preamble: softmax(W) -> LDS. Single exp pass, normalize in place.
    for (unsigned row = t; row < NUM_CLASSES; row += 1024u) {
        const float* w = W + row * OUT_DIM;
        float* p = P + row * OUT_DIM;
        float s = 0.f;
        #pragma unroll
        for (int j = 0; j < OUT_DIM; ++j) { const float v = __expf(w[j]); p[j] = v; s += v; }
        const float inv = 1.0f / s;
        #pragma unroll
        for (int j = 0; j < OUT_DIM; ++j) p[j] *= inv;
    }
    __syncthreads();

    // ---- Main loop: one float4 gather-store per iteration.
    // Element e -> row e/27, col e%27. A float4 spans row r0+1 iff c0 >= 24.
    unsigned i = blockIdx.x * blockDim.x + t;
    const unsigned stride = gridDim.x * blockDim.x;   // 524288: grid exactly resident, 54 iters
    for (; i < n4; i += stride) {
        const unsigned e  = i * 4u;
        const unsigned r0 = e / 27u;                  // magic-multiply
        const unsigned c0 = e - r0 * 27u;
        const unsigned r1 = r0 + (c0 >= 24u);
        // Both idx loads issued back-to-back (independent, mostly L1-hit).
        const unsigned base0 = (unsigned)idx[r0] * 27u;
        const unsigned base1 = (unsigned)idx[r1] * 27u;
        vfloat4 v;
        #pragma unroll
        for (int k = 0; k < 4; ++k) {
            const unsigned c = c0 + (unsigned)k;
            v[k] = P[(c < 27u) ? (base0 + c) : (base1 + c - 27u)];
        }
        *(vfloat4*)(out4 + i) = v;
    }
}

extern "C" void kernel_launch(void* const* d_in, const int* in_sizes, int n_in,
                              void* d_out, int out_size, void* d_ws, size_t ws_size,
                              hipStream_t stream) {
    const int*   idx = (const int*)d_in[0];   // bigram_idx [4194304] int32
    const float* W   = (const float*)d_in[1]; // W [601,27] float32
    float4*      out = (float4*)d_out;        // probs [4194304,27] float32

    const unsigned n4 = (unsigned)(out_size / 4);  // 28311552 float4 stores
    trigram_probs_kernel<<<dim3(512), dim3(1024), 0, stream>>>(idx, W, out, n4);
}